// Round 1
// 2941.136 us; speedup vs baseline: 1.2187x; 1.2187x over previous
//
#include <hip/hip_runtime.h>

typedef __bf16 bf16;
typedef bf16 bf16x8 __attribute__((ext_vector_type(8)));
typedef bf16 bf16x4 __attribute__((ext_vector_type(4)));
typedef float f32x4 __attribute__((ext_vector_type(4)));

#define MFMA16(a,b,c) __builtin_amdgcn_mfma_f32_16x16x32_bf16((a),(b),(c),0,0,0)

#define B_N 256
#define T_N 512
#define H_N 768
#define WROW 776      // 768 + 8 pad (bf16 elems)

// ---- device-global scratch (BSS) ----
__device__ float    g_ctrl[B_N * T_N];          // 512 KB
__device__ bf16     g_hbuf[2 * B_N * H_N];      // 768 KB (bf16 h exchange, intra-XCD L2)
__device__ unsigned g_flag[256 * 64];           // per-(block,set) flag, 128B apart (MALL atomics)
__device__ unsigned g_members[8 * 32];          // XCD roster -> blockIdx table
__device__ unsigned g_roster[8];
__device__ unsigned g_sync;

__device__ __forceinline__ float sigmoidf_(float x){ return 1.f/(1.f+__expf(-x)); }
__device__ __forceinline__ float tanhf_(float x){
  float e = __expf(-2.f*fabsf(x));
  float t = (1.f-e)/(1.f+e);
  return copysignf(t, x);
}
__device__ __forceinline__ float softplusf_(float x){
  return x > 20.f ? x : log1pf(__expf(x));
}
__device__ __forceinline__ bf16x8 ld_bf8(const float* p){
  f32x4 a = *(const f32x4*)p;
  f32x4 b = *(const f32x4*)(p + 4);
  bf16x8 v;
  v[0]=(bf16)a[0]; v[1]=(bf16)a[1]; v[2]=(bf16)a[2]; v[3]=(bf16)a[3];
  v[4]=(bf16)b[0]; v[5]=(bf16)b[1]; v[6]=(bf16)b[2]; v[7]=(bf16)b[3];
  return v;
}

__global__ void k_zero() {
  const int tid = threadIdx.x;
  for (int i = tid; i < 256*64; i += 256) g_flag[i] = 0u;
  if (tid < 256) g_members[tid] = 0u;   // fallback: block 0's flags (always advance)
  if (tid < 8)   g_roster[tid] = 0u;
  if (tid == 0)  g_sync = 0u;
}

// ---------------- kernel A: causal encoder Z + ctrl term (unchanged) ----------------
__global__ __launch_bounds__(256) void k_encode(
    const float* __restrict__ Xm, const float* __restrict__ Xc,
    const float* __restrict__ Aw,
    const float* __restrict__ ew1, const float* __restrict__ eb1,
    const float* __restrict__ ew2, const float* __restrict__ eb2,
    const float* __restrict__ nw,  const float* __restrict__ nb,
    const float* __restrict__ cw,  const float* __restrict__ cb,
    float* __restrict__ Zout)
{
  __shared__ float sA[16][16], sE1[16][32], sE2[16][16], sNW[16][32];
  __shared__ float sEB1[16], sEB2[16], sNB[16];
  __shared__ float sCW[768][16];
  __shared__ float sCB[768];
  const int tid = threadIdx.x;
  for (int i = tid; i < 256; i += 256) sA[i>>4][i&15] = Aw[i];
  for (int i = tid; i < 512; i += 256) sE1[i>>5][i&31] = ew1[i];
  for (int i = tid; i < 256; i += 256) sE2[i>>4][i&15] = ew2[i];
  for (int i = tid; i < 512; i += 256) sNW[i>>5][i&31] = nw[i];
  if (tid < 16) { sEB1[tid]=eb1[tid]; sEB2[tid]=eb2[tid]; sNB[tid]=nb[tid]; }
  for (int i = tid; i < 768*16; i += 256) sCW[i>>4][i&15] = cw[i];
  for (int i = tid; i < 768; i += 256) sCB[i] = cb[i];
  __syncthreads();
  const int idx = blockIdx.x*256 + tid;           // flat (b*T + t)
  const float* xmp = Xm + (size_t)idx*16;
  const float* xcp = Xc + (size_t)idx*16;
  float xm[16], xc[16];
  #pragma unroll
  for (int j=0;j<4;j++){
    *(f32x4*)&xm[j*4] = *(const f32x4*)(xmp + j*4);
    *(f32x4*)&xc[j*4] = *(const f32x4*)(xcp + j*4);
  }
  float snd[16], rcv[16];
  #pragma unroll
  for (int i=0;i<16;i++){
    float s=0.f, r=0.f;
    #pragma unroll
    for (int j=0;j<16;j++){ s += xm[j]*sA[i][j]; r += xm[j]*sA[j][i]; }
    snd[i]=s; rcv[i]=r;
  }
  float he[16];
  #pragma unroll
  for (int i=0;i<16;i++){
    float a = sEB1[i];
    #pragma unroll
    for (int k=0;k<16;k++) a += snd[k]*sE1[i][k];
    #pragma unroll
    for (int k=0;k<16;k++) a += rcv[k]*sE1[i][16+k];
    he[i] = fmaxf(a, 0.f);
  }
  float he2[16];
  #pragma unroll
  for (int i=0;i<16;i++){
    float a = sEB2[i];
    #pragma unroll
    for (int k=0;k<16;k++) a += he[k]*sE2[i][k];
    he2[i] = fmaxf(a, 0.f);
  }
  float* zp = Zout + (size_t)idx*16;
  #pragma unroll
  for (int m=0;m<16;m++){
    float a = sNB[m];
    #pragma unroll
    for (int k=0;k<16;k++) a += xm[k]*sNW[m][k];
    #pragma unroll
    for (int k=0;k<16;k++) a += he2[k]*sNW[m][16+k];
    zp[m] = fmaxf(a, 0.f);
  }
  float cs = 0.f;
  for (int i=0;i<768;i++){
    float a = sCB[i];
    #pragma unroll
    for (int k=0;k<16;k++) a += xc[k]*sCW[i][k];
    cs += fmaxf(a, 0.f);
  }
  g_ctrl[idx] = cs * 0.3f;
}

// ---------------- kernel B: adstock scan + hill + gru-input (unchanged) ----------------
__global__ __launch_bounds__(64) void k_adstock(
    const float* __restrict__ Xm, const float* __restrict__ alpha,
    const float* __restrict__ hill_a, const float* __restrict__ hill_g,
    float* __restrict__ Zio, float* __restrict__ hill_out)
{
  const int gid = blockIdx.x*64 + threadIdx.x;   // (b, m)
  const int b = gid >> 4, m = gid & 15;
  float a  = fminf(fmaxf(alpha[m],  0.f),  1.f);
  float ha = fminf(fmaxf(hill_a[m], 0.1f), 3.f);
  float hg = fminf(fmaxf(hill_g[m], 0.1f), 2.f);
  float gpow = __powf(hg, ha);
  const float* xp = Xm + (size_t)b*T_N*16 + m;
  float prev = 0.f, cmax = 0.f;
  for (int t=0;t<T_N;t++){ float x = xp[(size_t)t*16]; prev = x + a*prev; cmax = fmaxf(cmax, prev); }
  cmax = fmaxf(cmax, 1e-6f);
  float inv = 1.f/cmax;
  prev = 0.f;
  float* zp  = Zio      + (size_t)b*T_N*16 + m;
  float* hp  = hill_out + (size_t)b*T_N*16 + m;
  for (int t=0;t<T_N;t++){
    float x = xp[(size_t)t*16];
    prev = x + a*prev;
    float xn  = fmaxf(prev*inv, 0.f);
    float num = __powf(xn, ha);
    float h   = num / (num + gpow + 1e-8f);
    float z   = zp[(size_t)t*16];
    hp[(size_t)t*16] = h;
    zp[(size_t)t*16] = h + z;
  }
}

// ---------------- kernel C: persistent GRU + fused heads ----------------
// NEW vs round-polish baseline: each GRU step is split into two 16-batch
// phases (set A = group batches 0..15, set B = 16..31) with per-set flags.
// While phase B computes, set A's publish/flag round-trip (L2 drain + MALL
// flag + poll propagation) completes in the background -> the exchange RT
// is no longer exposed serial latency each step. h is staged ONCE per block
// into swizzled LDS (24KB) instead of 4 duplicated 24KB register volleys
// (per-XCD fan-out 3MB -> 1.5MB per step). Weights live in registers
// (2 tiles x 12 kt per wave) + one 32-row LDS tile (T2/T5).
// Row layout (local rows, per 24-dim slice j0=p*24):
//   0..23 r-gate | 24..47 z-gate | 48..71 n-gate | 72..87 head | 88..95 zero
// Tiles: T0 0-15, T1 16-31, T2 32-47 (r,z: input FOLDED via Wih MFMA)
//        T3 48-63, T4 64-79, T5 80-95 (n input kept separate in sGIN; head no input)
// Wave w: rg=w&1 (0: T0,T1 reg + T2 LDS; 1: T3,T4 reg + T5 LDS), kh=w>>1 (kt half).
__device__ __forceinline__ void poll_flags(unsigned midx, unsigned val) {
  int tries = 0;
  for (;;) {
    unsigned v = __hip_atomic_load(&g_flag[midx], __ATOMIC_RELAXED, __HIP_MEMORY_SCOPE_AGENT);
    if (__ballot(v >= val) == ~0ull) break;
    if (++tries > (1<<18)) break;               // fail-visible, never hang
    if (tries > 8) __builtin_amdgcn_s_sleep(1);
  }
  __builtin_amdgcn_fence(__ATOMIC_ACQUIRE, "workgroup");
}

__global__ __launch_bounds__(256, 1) void k_gru(
    const float* __restrict__ Xc,
    const float* __restrict__ Wih, const float* __restrict__ Whh,
    const float* __restrict__ bih, const float* __restrict__ bhh,
    const float* __restrict__ wraww, const float* __restrict__ wrawb,
    const float* __restrict__ regemb, const float* __restrict__ bias,
    const float* __restrict__ h0,
    float* __restrict__ hillZ,       // = outw region (read until step t, then w_pos)
    float* __restrict__ hill,        // = outc region (read hill, overwrite contrib)
    float* __restrict__ outy)
{
  __shared__ __align__(16) bf16 sW2[32*WROW];   // 49,664 B : T2 rows(0-15) + T5 rows(16-31)
  __shared__ __align__(16) bf16 sH[16*768];     // 24,576 B : staged h for active set (swizzled)
  __shared__ float sGH2[2][16][100];            // 12,800 B : partial D per kt-half
  __shared__ float sGIN[16][32];                //  2,048 B : n-gate + (garbage) input part
  __shared__ float sHm[32][26];                 //  3,328 B : f32 master h slice (both sets)
  __shared__ float sBih[72], sBhh[72];          //    576 B
  __shared__ float sWrb[16];                    //     64 B
  __shared__ float sScal[2];                    //      8 B
  __shared__ unsigned sGP[2];                   //      8 B   -> ~93 KB total (1 blk/CU)

  const int tid = threadIdx.x;
  const int wave = tid >> 6, lane = tid & 63;
  const int quad = lane >> 4, l16 = lane & 15;
  const int rg = wave & 1;
  const int kh = wave >> 1;

  // runtime group discovery: g = physical XCD
  if (tid == 0) {
    unsigned x;
    asm volatile("s_getreg_b32 %0, hwreg(HW_REG_XCC_ID, 0, 32)" : "=s"(x));
    x &= 7u;
    unsigned slot = __hip_atomic_fetch_add(&g_roster[x], 1u,
                        __ATOMIC_RELAXED, __HIP_MEMORY_SCOPE_AGENT);
    if (slot < 32u)
      __hip_atomic_store(&g_members[x*32u + slot], (unsigned)blockIdx.x,
                         __ATOMIC_RELAXED, __HIP_MEMORY_SCOPE_AGENT);
    sGP[0] = x; sGP[1] = slot & 31u;
    __hip_atomic_fetch_add(&g_sync, 1u, __ATOMIC_RELEASE, __HIP_MEMORY_SCOPE_AGENT);
    int tries = 0;
    while (__hip_atomic_load(&g_sync, __ATOMIC_ACQUIRE, __HIP_MEMORY_SCOPE_AGENT) < 256u) {
      if (++tries > (1<<20)) break;
      __builtin_amdgcn_s_sleep(1);
    }
  }
  __syncthreads();
  const int g = (int)sGP[0], p = (int)sGP[1];
  const int j0 = p*24;
  const int s_own = (p >= 16) ? 1 : 0;          // which set owns batch bq
  const int bqL = p & 15;                       // bq's row within its set's M-tile
  const int bq = g*32 + p;
  const unsigned member = __hip_atomic_load(&g_members[g*32 + (lane & 31)],
                              __ATOMIC_RELAXED, __HIP_MEMORY_SCOPE_AGENT);
  const unsigned midx0 = member * 64u;          // +s*32 selects the set's flag line
  const unsigned myflag = (unsigned)blockIdx.x * 64u;

  // ---- stage sW2: rows 0..15 = local rows 32..47 (T2), 16..31 = local 80..95 (T5)
  for (int c = tid; c < 32*192; c += 256) {
    int rl = c / 192, off = (c - rl*192)*4;
    int L = (rl < 16) ? (32 + rl) : (64 + rl);  // rl>=16 -> 80 + (rl-16)
    f32x4 w;
    if (L < 72)      w = *(const f32x4*)&Whh[(size_t)((L/24)*768 + j0 + (L%24))*768 + off];
    else if (L < 88) w = *(const f32x4*)&wraww[(size_t)(L-72)*768 + off];
    else             { w[0]=0.f; w[1]=0.f; w[2]=0.f; w[3]=0.f; }
    bf16x4 v; v[0]=(bf16)w[0]; v[1]=(bf16)w[1]; v[2]=(bf16)w[2]; v[3]=(bf16)w[3];
    *(bf16x4*)&sW2[rl*WROW + off] = v;
  }
  if (tid < 72) {
    int grow = (tid/24)*768 + j0 + (tid%24);
    sBih[tid] = bih[grow];
    sBhh[tid] = bhh[grow];
  }
  if (tid >= 128 && tid < 144) sWrb[tid-128] = wrawb[tid-128];
  if (wave == 0) {
    float sacc = 0.f;
    for (int k = lane; k < 768; k += 64) sacc += regemb[k];  // reg_emb[0]
    #pragma unroll
    for (int off = 32; off; off >>= 1) sacc += __shfl_xor(sacc, off, 64);
    if (lane == 0) { sScal[0] = 0.3f*sacc; sScal[1] = bias[0]; }
  }

  // ---- per-wave register weight fragments (t-invariant) ----
  // bw0 = tile (rg? T3:T0), bw1 = tile (rg? T4:T1), 12 kt each.
  bf16x8 bw0[12], bw1[12];
  {
    const int LA = (rg ? 48 : 0) + l16;               // < 72 always
    const int LB = (rg ? 64 : 16) + l16;              // rg1,l16>=8 -> head rows 72..79
    const float* rowA = Whh + (size_t)((LA/24)*768 + j0 + (LA%24))*768;
    const float* rowB = (LB < 72)
        ? (Whh + (size_t)((LB/24)*768 + j0 + (LB%24))*768)
        : (wraww + (size_t)(LB-72)*768);
    #pragma unroll
    for (int kk = 0; kk < 12; kk++) {
      const int col = (kh*12 + kk)*32 + quad*8;
      bw0[kk] = ld_bf8(rowA + col);
      bw1[kk] = ld_bf8(rowB + col);
    }
  }
  // Wih fragments (kh==0 waves only). Head rows (>=72) have no input -> zero.
  bf16x8 wf0, wf1, wf2;
  #pragma unroll
  for (int i = 0; i < 8; i++) { wf0[i]=(bf16)0.f; wf1[i]=(bf16)0.f; wf2[i]=(bf16)0.f; }
  if (kh == 0) {
    const int base = rg ? 48 : 0;
    {
      const int L = base + l16;                       // 0-15 or 48-63
      wf0 = ld_bf8(Wih + (size_t)((L/24)*768 + j0 + (L%24))*32 + quad*8);
    }
    {
      const int L = base + 16 + l16;                  // 16-31 or 64-79
      if (L < 72)
        wf1 = ld_bf8(Wih + (size_t)((L/24)*768 + j0 + (L%24))*32 + quad*8);
    }
    if (rg == 0) {
      const int L = 32 + l16;                         // 32-47
      wf2 = ld_bf8(Wih + (size_t)((L/24)*768 + j0 + (L%24))*32 + quad*8);
    }
  }

  // ---- init h (parity 0): f32 master + bf16 publish (both sets) ----
  {
    unsigned* hb = (unsigned*)g_hbuf;
    for (int e = tid; e < 384; e += 256) {
      int b = e/12, j = (e - b*12)*2;
      float f0 = h0[j0+j], f1 = h0[j0+j+1];
      sHm[b][j] = f0; sHm[b][j+1] = f1;
      union { bf16 h[2]; unsigned u; } pk;
      pk.h[0] = (bf16)f0; pk.h[1] = (bf16)f1;
      hb[((size_t)(g*32+b)*H_N + j0 + j) >> 1] = pk.u;
    }
  }
  __syncthreads();   // drains init publishes (vmcnt(0)) + LDS staging
  if (tid == 0) {
    __hip_atomic_store(&g_flag[myflag],      1u, __ATOMIC_RELAXED, __HIP_MEMORY_SCOPE_AGENT);
    __hip_atomic_store(&g_flag[myflag + 32], 1u, __ATOMIC_RELAXED, __HIP_MEMORY_SCOPE_AGENT);
  }
  const float regt = sScal[0], bias0 = sScal[1];

  float wp0_r = 0.f, hl0_r = 0.f, ct0_r = 0.f;  // t=0 state (lanes tid<16)

  // prologue: prefetch x for phase (s=0, t=0) and hill/ctrl(0)
  f32x4 xf0, xf1;
  xf0[0]=0.f; xf0[1]=0.f; xf0[2]=0.f; xf0[3]=0.f; xf1 = xf0;
  if (kh == 0) {
    const int gb0 = g*32 + l16;
    const float* hz = hillZ + (size_t)gb0*T_N*16;
    const float* xr = Xc    + (size_t)gb0*T_N*16;
    const float* src = (quad < 2) ? (hz + quad*8) : (xr + (quad-2)*8);
    xf0 = *(const f32x4*)src;
    xf1 = *(const f32x4*)(src + 4);
  }
  float hl_pf = 0.f, ct_pf = 0.f;
  if (tid < 16) {
    hl_pf = hill[(size_t)bq*T_N*16 + tid];
    if (tid == 0) ct_pf = g_ctrl[(size_t)bq*T_N];
  }

  const bf16* hb_base = g_hbuf;
  const int rl3 = (rg ? 16 : 0) + l16;          // sW2 row of the LDS tile (T2 / T5)
  const int swz = (l16 & 7) << 3;               // bank-conflict swizzle (elem units)
  int par = 0;

  #pragma unroll 1
  for (int t = 0; t < T_N; t++) {
    #pragma unroll 1
    for (int s = 0; s < 2; s++) {
      // wait: all group members published h_{t-1} of this set
      poll_flags(midx0 + (unsigned)(s*32), (unsigned)(t + 1));
      // cooperative volley -> swizzled LDS (one copy per block)
      {
        const int gbv = g*32 + s*16 + l16;
        const bf16* hsrc = hb_base + (size_t)par*B_N*H_N + (size_t)gbv*H_N + quad*8;
        bf16x8 hv[6];
        #pragma unroll
        for (int j = 0; j < 6; j++) {
          asm volatile("global_load_dwordx4 %0, %1, off sc0"
                       : "=v"(hv[j]) : "v"(hsrc + (wave*6 + j)*32) : "memory");
        }
        asm volatile("s_waitcnt vmcnt(0)"
            : "+v"(hv[0]),"+v"(hv[1]),"+v"(hv[2]),"+v"(hv[3]),"+v"(hv[4]),"+v"(hv[5])
            :: "memory");
        bf16* dst = &sH[l16*768];
        #pragma unroll
        for (int j = 0; j < 6; j++) {
          const int cv = wave*6 + j;
          *(bf16x8*)&dst[(cv*32 + quad*8) ^ swz] = hv[j];
        }
      }
      // build ax from last phase's x prefetch (kh0 waves)
      bf16x8 ax;
      if (kh == 0) {
        ax[0]=(bf16)xf0[0]; ax[1]=(bf16)xf0[1]; ax[2]=(bf16)xf0[2]; ax[3]=(bf16)xf0[3];
        ax[4]=(bf16)xf1[0]; ax[5]=(bf16)xf1[1]; ax[6]=(bf16)xf1[2]; ax[7]=(bf16)xf1[3];
      }
      __syncthreads();   // B1: volley visible to all waves
      f32x4 a0; a0[0]=0.f; a0[1]=0.f; a0[2]=0.f; a0[3]=0.f;
      f32x4 a1 = a0, a2 = a0, gi0 = a0, gi1 = a0;
      if (kh == 0) {
        if (rg == 0) {   // r,z rows: fold input into hidden accumulators
          a0 = MFMA16(ax, wf0, a0);
          a1 = MFMA16(ax, wf1, a1);
          a2 = MFMA16(ax, wf2, a2);
        } else {         // n rows: input kept separate (needed for r*hn)
          gi0 = MFMA16(ax, wf0, gi0);
          gi1 = MFMA16(ax, wf1, gi1);
        }
      }
      // prefetch x for next phase (hides under MFMA burst)
      if (kh == 0) {
        const int sn = s ^ 1;
        int tn = (s == 1) ? t + 1 : t;
        if (tn >= T_N) tn = T_N - 1;
        const int gbn = g*32 + sn*16 + l16;
        const float* hz = hillZ + ((size_t)gbn*T_N + tn)*16;
        const float* xr = Xc    + ((size_t)gbn*T_N + tn)*16;
        const float* src = (quad < 2) ? (hz + quad*8) : (xr + (quad-2)*8);
        xf0 = *(const f32x4*)src;
        xf1 = *(const f32x4*)(src + 4);
      }
      // gh += h @ W_hh^T over this wave's kt half
      {
        const bf16* hrow = &sH[l16*768];
        #pragma unroll
        for (int kk = 0; kk < 12; kk++) {
          const int kt = kh*12 + kk;
          bf16x8 ha = *(const bf16x8*)&hrow[(kt*32 + quad*8) ^ swz];
          a0 = MFMA16(ha, bw0[kk], a0);
          a1 = MFMA16(ha, bw1[kk], a1);
          a2 = MFMA16(ha, *(const bf16x8*)&sW2[rl3*WROW + kt*32 + quad*8], a2);
        }
      }
      // stage D fragments (partial sums per kt-half)
      {
        const int c0 = rg*48 + l16;
        #pragma unroll
        for (int r = 0; r < 4; r++) {
          const int rb = quad*4 + r;             // batch within the phase's M-tile
          sGH2[kh][rb][c0]    = a0[r];
          sGH2[kh][rb][c0+16] = a1[r];
          sGH2[kh][rb][c0+32] = a2[r];
        }
        if (kh == 0 && rg == 1) {
          #pragma unroll
          for (int r = 0; r < 4; r++) {
            const int rb = quad*4 + r;
            sGIN[rb][l16]    = gi0[r];
            sGIN[rb][16+l16] = gi1[r];
          }
        }
      }
      __syncthreads();   // B2: staging complete
      const bool own = (s_own == s);
      float hd_s = 0.f;
      if (own && tid < 16) hd_s = sGH2[0][bqL][72+tid] + sGH2[1][bqL][72+tid];
      // gates -> h_new; f32 master feedback; plain-store publish (L2)
      if (tid >= 64) {
        const int e = tid - 64;                  // 0..191
        const int b = e / 12, jp = (e - b*12)*2;
        const int bg = s*16 + b;
        unsigned* hnxt = (unsigned*)(g_hbuf + (size_t)(1-par)*B_N*H_N);
        float hn0, hn1;
        {
          const int j = jp;
          float gh_r = sGH2[0][b][j]    + sGH2[1][b][j];
          float gh_z = sGH2[0][b][24+j] + sGH2[1][b][24+j];
          float gh_n = sGH2[0][b][48+j] + sGH2[1][b][48+j];
          float rr = sigmoidf_(gh_r + sBih[j]    + sBhh[j]);
          float zz = sigmoidf_(gh_z + sBih[24+j] + sBhh[24+j]);
          float nn = tanhf_(sGIN[b][j] + sBih[48+j] + rr*(gh_n + sBhh[48+j]));
          hn0 = (1.f-zz)*nn + zz*sHm[bg][j];
        }
        {
          const int j = jp + 1;
          float gh_r = sGH2[0][b][j]    + sGH2[1][b][j];
          float gh_z = sGH2[0][b][24+j] + sGH2[1][b][24+j];
          float gh_n = sGH2[0][b][48+j] + sGH2[1][b][48+j];
          float rr = sigmoidf_(gh_r + sBih[j]    + sBhh[j]);
          float zz = sigmoidf_(gh_z + sBih[24+j] + sBhh[24+j]);
          float nn = tanhf_(sGIN[b][j] + sBih[48+j] + rr*(gh_n + sBhh[48+j]));
          hn1 = (1.f-zz)*nn + zz*sHm[bg][j];
        }
        sHm[bg][jp] = hn0; sHm[bg][jp+1] = hn1;
        union { bf16 h[2]; unsigned u; } pk;
        pk.h[0] = (bf16)hn0; pk.h[1] = (bf16)hn1;
        hnxt[((size_t)(g*32+bg)*H_N + j0 + jp) >> 1] = pk.u;
      }
      __syncthreads();   // B3: vmcnt(0) drains publishes into L2
      if (tid == 0)
        __hip_atomic_store(&g_flag[myflag + s*32], (unsigned)(t + 2),
                           __ATOMIC_RELAXED, __HIP_MEMORY_SCOPE_AGENT);
      // ---- deferred epilogue for tt = t-1 (owning phase only) ----
      if (own) {
        if (t > 0 && tid < 16) {
          const int tt = t - 1;
          float wp = softplusf_(hd_s + sWrb[tid]);
          float hl = hl_pf;
          if (tt == 0) { wp0_r = wp; hl0_r = hl; ct0_r = ct_pf; }
          else {
            size_t o = (size_t)bq*T_N + tt;
            float cv = hl*wp;
            hillZ[o*16 + tid] = wp;
            hill[o*16 + tid]  = cv;
            float cs = cv;
            cs += __shfl_xor(cs, 8, 64);
            cs += __shfl_xor(cs, 4, 64);
            cs += __shfl_xor(cs, 2, 64);
            cs += __shfl_xor(cs, 1, 64);
            if (tid == 0) outy[o] = cs + ct_pf + regt + bias0;
            if (tt == 1) {
              float w0 = 0.5f*(wp + wp0_r);
              float c0v = hl0_r*w0;
              size_t o0 = (size_t)bq*T_N;
              hillZ[o0*16 + tid] = w0;
              hill[o0*16 + tid]  = c0v;
              float cs0 = c0v;
              cs0 += __shfl_xor(cs0, 8, 64);
              cs0 += __shfl_xor(cs0, 4, 64);
              cs0 += __shfl_xor(cs0, 2, 64);
              cs0 += __shfl_xor(cs0, 1, 64);
              if (tid == 0) outy[o0] = cs0 + ct0_r + regt + bias0;
            }
          }
        }
        if (tid < 16) {
          hl_pf = hill[((size_t)bq*T_N + t)*16 + tid];
          if (tid == 0) ct_pf = g_ctrl[(size_t)bq*T_N + t];
        }
      }
    }
    par ^= 1;
  }

  // ---- tail: head for tt = T-1 from h_seq[T-1] (own set only; cold path) ----
  {
    const int s = s_own;
    poll_flags(midx0 + (unsigned)(s*32), (unsigned)(T_N + 1));
    {
      const int gbv = g*32 + s*16 + l16;
      const bf16* hsrc = hb_base + (size_t)par*B_N*H_N + (size_t)gbv*H_N + quad*8;
      bf16x8 hv[6];
      #pragma unroll
      for (int j = 0; j < 6; j++) {
        asm volatile("global_load_dwordx4 %0, %1, off sc0"
                     : "=v"(hv[j]) : "v"(hsrc + (wave*6 + j)*32) : "memory");
      }
      asm volatile("s_waitcnt vmcnt(0)"
          : "+v"(hv[0]),"+v"(hv[1]),"+v"(hv[2]),"+v"(hv[3]),"+v"(hv[4]),"+v"(hv[5])
          :: "memory");
      bf16* dst = &sH[l16*768];
      #pragma unroll
      for (int j = 0; j < 6; j++) {
        const int cv = wave*6 + j;
        *(bf16x8*)&dst[(cv*32 + quad*8) ^ swz] = hv[j];
      }
    }
    __syncthreads();
    if (rg == 1) {
      f32x4 a1; a1[0]=0.f; a1[1]=0.f; a1[2]=0.f; a1[3]=0.f;
      f32x4 a2 = a1;
      const bf16* hrow = &sH[l16*768];
      #pragma unroll
      for (int kk = 0; kk < 12; kk++) {
        const int kt = kh*12 + kk;
        bf16x8 ha = *(const bf16x8*)&hrow[(kt*32 + quad*8) ^ swz];
        a1 = MFMA16(ha, bw1[kk], a1);
        a2 = MFMA16(ha, *(const bf16x8*)&sW2[(16+l16)*WROW + kt*32 + quad*8], a2);
      }
      #pragma unroll
      for (int r = 0; r < 4; r++) {
        const int rb = quad*4 + r;
        sGH2[kh][rb][64 + l16] = a1[r];
        sGH2[kh][rb][80 + l16] = a2[r];
      }
    }
    __syncthreads();
    if (tid < 16) {
      const int tt = T_N - 1;
      float hd = sGH2[0][bqL][72+tid] + sGH2[1][bqL][72+tid];
      float wp = softplusf_(hd + sWrb[tid]);
      float hl = hill[((size_t)bq*T_N + tt)*16 + tid];
      size_t o = (size_t)bq*T_N + tt;
      float cv = hl*wp;
      hillZ[o*16 + tid] = wp;
      hill[o*16 + tid]  = cv;
      float cs = cv;
      cs += __shfl_xor(cs, 8, 64);
      cs += __shfl_xor(cs, 4, 64);
      cs += __shfl_xor(cs, 2, 64);
      cs += __shfl_xor(cs, 1, 64);
      if (tid == 0) outy[o] = cs + g_ctrl[o] + regt + bias0;
    }
  }
}

extern "C" void kernel_launch(void* const* d_in, const int* in_sizes, int n_in,
                              void* d_out, int out_size, void* d_ws, size_t ws_size,
                              hipStream_t stream) {
  const float* Xm    = (const float*)d_in[0];
  const float* Xc    = (const float*)d_in[1];
  const float* Aw    = (const float*)d_in[3];
  const float* ew1   = (const float*)d_in[4];
  const float* eb1   = (const float*)d_in[5];
  const float* ew2   = (const float*)d_in[6];
  const float* eb2   = (const float*)d_in[7];
  const float* nw    = (const float*)d_in[8];
  const float* nb    = (const float*)d_in[9];
  const float* Wih   = (const float*)d_in[10];
  const float* Whh   = (const float*)d_in[11];
  const float* bih   = (const float*)d_in[12];
  const float* bhh   = (const float*)d_in[13];
  const float* wraww = (const float*)d_in[14];
  const float* wrawb = (const float*)d_in[15];
  const float* alpha = (const float*)d_in[16];
  const float* hilla = (const float*)d_in[17];
  const float* hillg = (const float*)d_in[18];
  const float* cw    = (const float*)d_in[19];
  const float* cb    = (const float*)d_in[20];
  const float* regemb= (const float*)d_in[21];
  const float* bias  = (const float*)d_in[22];
  const float* h0    = (const float*)d_in[23];

  float* outy = (float*)d_out;
  float* outw = outy + 256*512;          // doubles as Z / hillZ scratch
  float* outc = outw + 256*512*16;       // doubles as hill scratch

  k_zero<<<1, 256, 0, stream>>>();
  k_encode<<<512, 256, 0, stream>>>(Xm, Xc, Aw, ew1, eb1, ew2, eb2, nw, nb, cw, cb,
                                    outw);
  k_adstock<<<64, 64, 0, stream>>>(Xm, alpha, hilla, hillg, outw, outc);
  // Plain launch: grid==256 CUs + ~93KB-LDS (1 blk/CU) => all blocks co-resident.
  k_gru<<<dim3(256), dim3(256), 0, stream>>>(
      Xc, Wih, Whh, bih, bhh, wraww, wrawb, regemb, bias, h0,
      outw, outc, outy);
}